// Round 7
// baseline (977.061 us; speedup 1.0000x reference)
//
#include <hip/hip_runtime.h>

typedef __attribute__((ext_vector_type(8)))  short bf16x8;   // 8 bf16 = 4 VGPR MFMA operand
typedef __attribute__((ext_vector_type(16))) float f32x16;   // 32x32 MFMA accumulator

#define XIM (32*256*256)
#define MAXFIX 16384

__device__ __forceinline__ short f2bf(float f){
    unsigned int u = __builtin_bit_cast(unsigned int, f);
    u += 0x7fffu + ((u >> 16) & 1u);           // RNE, no NaN inputs here
    return (short)(u >> 16);
}
__device__ __forceinline__ float bf2f(short s){
    unsigned int u = ((unsigned int)(unsigned short)s) << 16;
    return __builtin_bit_cast(float, u);
}
__device__ __forceinline__ void glds16(const short* g, short* l){
    __builtin_amdgcn_global_load_lds(
        (const __attribute__((address_space(1))) unsigned int*)g,
        (__attribute__((address_space(3))) unsigned int*)l,
        16, 0, 0);
}

__global__ void zero_cnt(int* cnt){ if(threadIdx.x == 0) *cnt = 0; }

// ---- prep: weights -> bf16 wt2[es(10)][tap(9)][cio(4)][cout(32)][8ci]; + biasmat[c(32)][k(16)] ----
__global__ __launch_bounds__(256) void prep_weights(const float* __restrict__ ew,
                                                    const float* __restrict__ sw,
                                                    const float* __restrict__ ebv,
                                                    const float* __restrict__ sbv,
                                                    short* __restrict__ wt2){
    int i = blockIdx.x * 256 + threadIdx.x;      // 362 blocks
    if(i < 92160){
        int c7  = i & 7;
        int col = (i >> 3) & 31;                 // cout
        int cio = (i >> 8) & 3;                  // ci octet
        int rest = i >> 10;                      // 0..89
        int tap = rest % 9;
        int es  = rest / 9;                      // 0..9
        int ci  = cio*8 + c7;
        float v;
        if(es < 8)       v = ew[((es*32 + col)*32 + ci)*9 + tap];
        else if(es == 8) v = sw[(col*32 + ci)*9 + tap];
        else             v = 0.f;
        wt2[i] = f2bf(v);
    } else if(i < 92160 + 512){                  // biasmat: k<8 -> eb[k][c], k==8 -> sb[c], else 0
        int j = i - 92160, c = j >> 4, k = j & 15;
        float v = (k < 8) ? ebv[k*32 + c] : ((k == 8) ? sbv[c] : 0.f);
        wt2[i] = f2bf(v);
    }
}

// ---- gate: 2048 blocks x 1 row; LDS-tiled fp32 conv -> sigmoid -> top2 -> softmax -> route ----
__global__ __launch_bounds__(256) void gate_kernel(const float* __restrict__ x,
                                                   const float* __restrict__ gw,
                                                   const float* __restrict__ gb,
                                                   short* __restrict__ route,
                                                   int* __restrict__ cnt,
                                                   int* __restrict__ fixlist){
    __shared__ float xs[24][264];                // [r3*8+ci][4+xx], 25.3 KB
    int raw = blockIdx.x;                        // 2048; XCD chunk swizzle (2048%8==0)
    int wg  = (raw & 7)*256 + (raw >> 3);
    int b   = wg >> 8;
    int y   = wg & 255;
    int t   = threadIdx.x;
    int wv  = t >> 6, lane = t & 63;
    const float* xim = x + (size_t)b * XIM;

    if(t < 48){                                  // edge zeros (xx=-1 -> [3], xx=256 -> [260]); persist
        int s2 = t >> 1;
        if(t & 1) xs[s2][260] = 0.f; else xs[s2][3] = 0.f;
    }

    float g[8];
    #pragma unroll
    for(int e=0;e<8;++e) g[e] = 0.f;

    for(int cc=0; cc<4; ++cc){                   // ci chunks of 8
        __syncthreads();                         // prev reads done (also publishes edge zeros)
        #pragma unroll
        for(int sg=0; sg<6; ++sg){               // wave stages 6 of 24 segments via float4
            int seg = wv*6 + sg;
            int r3  = seg >> 3;                  // rows y-1..y+1
            int ci  = (seg & 7) + cc*8;
            int yy  = y - 1 + r3;
            const float* xr = xim + ((size_t)ci*256 + yy)*256;
            float4 v = make_float4(0.f,0.f,0.f,0.f);
            if(yy >= 0 && yy < 256) v = *(const float4*)(xr + lane*4);
            *(float4*)(&xs[seg][4 + lane*4]) = v;
        }
        __syncthreads();
        #pragma unroll
        for(int ci=0; ci<8; ++ci){
            float sv[3][3];
            #pragma unroll
            for(int r3=0;r3<3;++r3){
                sv[r3][0] = xs[r3*8+ci][t+3];    // xx = t-1+kw -> idx xx+4 = t+3+kw
                sv[r3][1] = xs[r3*8+ci][t+4];
                sv[r3][2] = xs[r3*8+ci][t+5];
            }
            const float* gwp = gw + (cc*8 + ci)*9;     // gw[e][ci][kh][kw], e-stride 288
            #pragma unroll
            for(int e=0;e<8;++e){
                #pragma unroll
                for(int kh=0;kh<3;++kh){
                    #pragma unroll
                    for(int kw=0;kw<3;++kw){
                        g[e] = fmaf(sv[kh][kw], gwp[e*288 + kh*3 + kw], g[e]);
                    }
                }
            }
        }
    }

    {
        float v1b=-1e30f, v2b=-1e30f, v3b=-1e30f, r1=0.f, r2=0.f; int i1=-1, i2=-1;
        #pragma unroll
        for(int e=0;e<8;e++){
            float se = 1.f/(1.f + expf(-g[e]));
            float be = se + gb[e];
            if(be > v1b){ v3b=v2b; v2b=v1b; r2=r1; i2=i1; v1b=be; r1=se; i1=e; }
            else if(be > v2b){ v3b=v2b; v2b=be; r2=se; i2=e; }
            else if(be > v3b){ v3b=be; }
        }
        if(v2b - v3b < 2e-5f){                   // too close to call in fp32 -> fp64 fixup pass
            int slot = atomicAdd(cnt, 1);
            if(slot < MAXFIX) fixlist[slot] = (b << 16) | (y << 8) | t;
        }
        float m  = fmaxf(r1, r2);
        float e1 = expf(r1-m), e2 = expf(r2-m);
        float inv = 1.f/(e1+e2);
        float w1 = e1*inv, w2 = e2*inv;          // ROUTE_SCALE = 1
        bf16x8 ov;
        #pragma unroll
        for(int e=0;e<8;e++){
            float dv = (e==i1) ? w1 : ((e==i2) ? w2 : 0.f);
            ov[e] = f2bf(dv);
        }
        *(bf16x8*)(route + ((size_t)(b*256 + y)*256 + t)*8) = ov;
    }
}

// ---- fixup: fp64 re-selection for flagged pixels (rare) ----
__global__ __launch_bounds__(256) void fixup_kernel(const float* __restrict__ x,
                                                    const float* __restrict__ gw,
                                                    const float* __restrict__ gb,
                                                    const int* __restrict__ cnt,
                                                    const int* __restrict__ fixlist,
                                                    short* __restrict__ route){
    int n = *cnt; if(n > MAXFIX) n = MAXFIX;
    for(int idx = blockIdx.x*256 + threadIdx.x; idx < n; idx += 16*256){
        int pix = fixlist[idx];
        int b  = pix >> 16, y = (pix >> 8) & 255, xx = pix & 255;
        const float* xim = x + (size_t)b*XIM;
        double gd[8];
        #pragma unroll
        for(int e=0;e<8;e++) gd[e] = 0.0;
        for(int ci=0; ci<32; ++ci){
            for(int kh=0; kh<3; ++kh){
                int yy = y + kh - 1;
                if(yy < 0 || yy >= 256) continue;
                const float* xr = xim + ((size_t)ci*256 + yy)*256;
                for(int kw=0; kw<3; ++kw){
                    int xc = xx + kw - 1;
                    if(xc < 0 || xc >= 256) continue;
                    double xv = (double)xr[xc];
                    #pragma unroll
                    for(int e=0;e<8;e++) gd[e] += xv * (double)gw[e*288 + ci*9 + kh*3 + kw];
                }
            }
        }
        double b1=-1e30, b2=-1e30; double rr1=0.0, rr2=0.0; int j1=-1, j2=-1;
        #pragma unroll
        for(int e=0;e<8;e++){
            double sd = 1.0/(1.0 + exp(-gd[e]));
            double bd = sd + (double)gb[e];
            if(bd > b1){ b2=b1; rr2=rr1; j2=j1; b1=bd; rr1=sd; j1=e; }
            else if(bd > b2){ b2=bd; rr2=sd; j2=e; }
        }
        float r1 = (float)rr1, r2 = (float)rr2;
        float m  = fmaxf(r1, r2);
        float e1 = expf(r1-m), e2 = expf(r2-m);
        float inv = 1.f/(e1+e2);
        float w1 = e1*inv, w2 = e2*inv;
        bf16x8 ov;
        #pragma unroll
        for(int e=0;e<8;e++){
            float dv = (e==j1) ? w1 : ((e==j2) ? w2 : 0.f);
            ov[e] = f2bf(dv);
        }
        *(bf16x8*)(route + (size_t)pix*8) = ov;
    }
}

// ---- main: 512-thr blocks, wave = 1 output row; B-frags in regs, A via glds dbuf, bias MFMA ----
// Block tile: 8 rows x 32 cols; 8 waves. MFMA 32x32x16: A=weights(M=cout), B=x(N=px).
__global__ __launch_bounds__(512, 4) void moe_main(const float* __restrict__ x,
                                                   const short* __restrict__ wt2,
                                                   const short* __restrict__ route,
                                                   float* __restrict__ out){
    __shared__ __align__(16) short xt[10*4*34*8];    // [row10][cio4][px34][8ci] bf16, 21.76 KB
    __shared__ __align__(16) short wlds[2*9216];     // dbuf: [tap9][cio4][cout32][8ci], 2x18 KB
    int raw = blockIdx.x;                            // 2048; XCD chunk swizzle
    int wg  = (raw & 7)*256 + (raw >> 3);
    int b   = wg >> 8;
    int y0  = ((wg >> 3) & 31) * 8;
    int x0  = (wg & 7) * 32;
    int t   = threadIdx.x;                           // 0..511
    int wv  = t >> 6, l = t & 63, col = l & 31, hi = l >> 5;

    // issue async stage of expert 0 -> buf0 (overlaps x staging); 18 chunks over 8 waves
    #pragma unroll
    for(int j=0;j<3;++j){
        int chunk = wv + 8*j;                        // wave-uniform predicate
        if(chunk < 18) glds16(wt2 + chunk*512 + l*8, wlds + chunk*512);
    }

    const float* xim = x + (size_t)b*XIM;
    {   // stage x tile (with halo) -> bf16 LDS; 320 segments over 16 half-waves
        int px = t & 31, hw = t >> 5;
        #pragma unroll 4
        for(int i=0;i<20;i++){
            int pair = i*16 + hw;                    // row*32+ci
            int row = pair >> 5, ci = pair & 31;
            int yy = y0 - 1 + row, xx = x0 - 1 + px;
            float v = (yy>=0 && yy<256 && xx>=0 && xx<256) ? xim[((size_t)ci*256+yy)*256+xx] : 0.f;
            xt[((row*4 + (ci>>3))*34 + px)*8 + (ci&7)] = f2bf(v);
        }
    }
    #pragma unroll
    for(int k=0;k<2;k++){                            // halo cols px=32,33 (640 elems)
        int p = t + k*512;
        if(p < 640){
            int pair = p >> 1, px = 32 + (p & 1);
            int row = pair >> 5, ci = pair & 31;
            int yy = y0 - 1 + row, xx = x0 - 1 + px;
            float v = (yy>=0 && yy<256 && xx>=0 && xx<256) ? xim[((size_t)ci*256+yy)*256+xx] : 0.f;
            xt[((row*4 + (ci>>3))*34 + px)*8 + (ci&7)] = f2bf(v);
        }
    }
    bf16x8 biasA = *(const bf16x8*)(wt2 + 92160 + col*16 + hi*8);   // biasmat[c][k] frag

    __syncthreads();                                 // xt + expert0 staged (drains vmcnt+lgkmcnt)

    // B fragments -> registers, read ONCE (shared by all 9 experts): 18 ds_read_b128
    // output row y0+wv needs xt rows wv..wv+2 (global y0+wv-1 .. y0+wv+1)
    bf16x8 Bf[3][2][3];                              // [kh][ci-half][kw]
    #pragma unroll
    for(int kh=0;kh<3;++kh)
        #pragma unroll
        for(int hf=0;hf<2;++hf)
            #pragma unroll
            for(int kw=0;kw<3;++kw)
                Bf[kh][hf][kw] = *(const bf16x8*)(&xt[(((wv+kh)*4 + hf*2 + hi)*34 + col + kw)*8]);

    int yy = y0 + wv;
    bf16x8 rfrag = *(const bf16x8*)(route + ((size_t)(b*256 + yy)*256 + x0 + col)*8);
    bf16x8 ones = {};
    ones[0] = (short)0x3F80;                         // bf16 1.0 (k=8 row selects sb)
    f32x16 z = {};
    f32x16 oa = __builtin_amdgcn_mfma_f32_32x32x16_bf16(biasA, hi ? ones : rfrag, z, 0,0,0);

    #pragma unroll
    for(int e=0; e<9; ++e){                          // experts 0..7, then shared (8)
        const int cur = e & 1;
        if(e < 8){                                   // prefetch next expert -> other buffer
            const short* src = wt2 + (e+1)*9216;
            short* dst = wlds + (cur^1)*9216;
            #pragma unroll
            for(int j=0;j<3;++j){
                int chunk = wv + 8*j;
                if(chunk < 18) glds16(src + chunk*512 + l*8, dst + chunk*512);
            }
        }
        const short* wb = wlds + cur*9216;
        f32x16 acc = {};
        #pragma unroll
        for(int s=0; s<18; ++s){                     // K=288: tap=s>>1, ci-half=s&1
            const int tap = s >> 1;
            const int kh = tap/3, kw = tap - kh*3, hf = s & 1;
            bf16x8 a = *(const bf16x8*)(&wb[((tap*4 + hf*2 + hi)*32 + col)*8]);
            acc = __builtin_amdgcn_mfma_f32_32x32x16_bf16(a, Bf[kh][hf][kw], acc, 0,0,0);
        }
        float d = (e < 8) ? bf2f(rfrag[e]) : 1.0f;
        #pragma unroll
        for(int r=0;r<16;r++) oa[r] += d*acc[r];
        if(e < 8) __syncthreads();                   // next buf staged; cur reads done before overwrite
    }

    float* ob = out + (size_t)b*XIM;
    #pragma unroll
    for(int r=0;r<16;r++){
        int c = hi*4 + (r&3) + 8*(r>>2);             // C/D: col=lane&31, row=(r&3)+8*(r>>2)+4*hi
        ob[((size_t)c*256 + yy)*256 + x0 + col] = oa[r];
    }
}

extern "C" void kernel_launch(void* const* d_in, const int* in_sizes, int n_in,
                              void* d_out, int out_size, void* d_ws, size_t ws_size,
                              hipStream_t stream){
    (void)in_sizes; (void)n_in; (void)out_size; (void)ws_size;
    const float* x   = (const float*)d_in[0];
    const float* gw  = (const float*)d_in[1];
    const float* gb  = (const float*)d_in[2];
    const float* ew  = (const float*)d_in[3];
    const float* ebv = (const float*)d_in[4];
    const float* sw  = (const float*)d_in[5];
    const float* sbv = (const float*)d_in[6];
    float* out = (float*)d_out;

    short* route = (short*)d_ws;                          // 524288 px * 8 bf16 = 8.39 MB
    short* wt2   = route + (size_t)8*256*256*8;           // 92160 + 512 bf16
    int*   cnt   = (int*)(wt2 + 92672);
    int*   fixlist = cnt + 1;                             // MAXFIX ints

    zero_cnt    <<<dim3(1),    dim3(64),  0, stream>>>(cnt);
    prep_weights<<<dim3(362),  dim3(256), 0, stream>>>(ew, sw, ebv, sbv, wt2);
    gate_kernel <<<dim3(2048), dim3(256), 0, stream>>>(x, gw, gb, route, cnt, fixlist);
    fixup_kernel<<<dim3(16),   dim3(256), 0, stream>>>(x, gw, gb, cnt, fixlist, route);
    moe_main    <<<dim3(2048), dim3(512), 0, stream>>>(x, wt2, route, out);
}

// Round 8
// 413.411 us; speedup vs baseline: 2.3634x; 2.3634x over previous
//
#include <hip/hip_runtime.h>

typedef __attribute__((ext_vector_type(8)))  short bf16x8;   // 8 bf16 = 4 VGPR MFMA operand
typedef __attribute__((ext_vector_type(16))) float f32x16;   // 32x32 MFMA accumulator

#define XIM (32*256*256)
#define MAXFIX 16384

__device__ __forceinline__ short f2bf(float f){
    unsigned int u = __builtin_bit_cast(unsigned int, f);
    u += 0x7fffu + ((u >> 16) & 1u);           // RNE, no NaN inputs here
    return (short)(u >> 16);
}
__device__ __forceinline__ float bf2f(short s){
    unsigned int u = ((unsigned int)(unsigned short)s) << 16;
    return __builtin_bit_cast(float, u);
}
__device__ __forceinline__ void glds16(const short* g, short* l){
    __builtin_amdgcn_global_load_lds(
        (const __attribute__((address_space(1))) unsigned int*)g,
        (__attribute__((address_space(3))) unsigned int*)l,
        16, 0, 0);
}

__global__ void zero_cnt(int* cnt){ if(threadIdx.x == 0) *cnt = 0; }

// ---- prep: weights -> bf16 wt2[es(10)][tap(9)][cio(4)][cout(32)][8ci]; + biasmat[c(32)][k(16)] ----
__global__ __launch_bounds__(256) void prep_weights(const float* __restrict__ ew,
                                                    const float* __restrict__ sw,
                                                    const float* __restrict__ ebv,
                                                    const float* __restrict__ sbv,
                                                    short* __restrict__ wt2){
    int i = blockIdx.x * 256 + threadIdx.x;      // 362 blocks
    if(i < 92160){
        int c7  = i & 7;
        int col = (i >> 3) & 31;                 // cout
        int cio = (i >> 8) & 3;                  // ci octet
        int rest = i >> 10;                      // 0..89
        int tap = rest % 9;
        int es  = rest / 9;                      // 0..9
        int ci  = cio*8 + c7;
        float v;
        if(es < 8)       v = ew[((es*32 + col)*32 + ci)*9 + tap];
        else if(es == 8) v = sw[(col*32 + ci)*9 + tap];
        else             v = 0.f;
        wt2[i] = f2bf(v);
    } else if(i < 92160 + 512){                  // biasmat: k<8 -> eb[k][c], k==8 -> sb[c], else 0
        int j = i - 92160, c = j >> 4, k = j & 15;
        float v = (k < 8) ? ebv[k*32 + c] : ((k == 8) ? sbv[c] : 0.f);
        wt2[i] = f2bf(v);
    }
}

// ---- gate: 2048 blocks x 1 row; LDS-tiled fp32 conv -> sigmoid -> top2 -> softmax -> route ----
__global__ __launch_bounds__(256) void gate_kernel(const float* __restrict__ x,
                                                   const float* __restrict__ gw,
                                                   const float* __restrict__ gb,
                                                   short* __restrict__ route,
                                                   int* __restrict__ cnt,
                                                   int* __restrict__ fixlist){
    __shared__ float xs[24][264];                // [r3*8+ci][4+xx], 25.3 KB
    int raw = blockIdx.x;                        // 2048; XCD chunk swizzle (2048%8==0)
    int wg  = (raw & 7)*256 + (raw >> 3);
    int b   = wg >> 8;
    int y   = wg & 255;
    int t   = threadIdx.x;
    int wv  = t >> 6, lane = t & 63;
    const float* xim = x + (size_t)b * XIM;

    if(t < 48){                                  // edge zeros (xx=-1 -> [3], xx=256 -> [260]); persist
        int s2 = t >> 1;
        if(t & 1) xs[s2][260] = 0.f; else xs[s2][3] = 0.f;
    }

    float g[8];
    #pragma unroll
    for(int e=0;e<8;++e) g[e] = 0.f;

    for(int cc=0; cc<4; ++cc){                   // ci chunks of 8
        __syncthreads();                         // prev reads done (also publishes edge zeros)
        #pragma unroll
        for(int sg=0; sg<6; ++sg){               // wave stages 6 of 24 segments via float4
            int seg = wv*6 + sg;
            int r3  = seg >> 3;                  // rows y-1..y+1
            int ci  = (seg & 7) + cc*8;
            int yy  = y - 1 + r3;
            const float* xr = xim + ((size_t)ci*256 + yy)*256;
            float4 v = make_float4(0.f,0.f,0.f,0.f);
            if(yy >= 0 && yy < 256) v = *(const float4*)(xr + lane*4);
            *(float4*)(&xs[seg][4 + lane*4]) = v;
        }
        __syncthreads();
        #pragma unroll
        for(int ci=0; ci<8; ++ci){
            float sv[3][3];
            #pragma unroll
            for(int r3=0;r3<3;++r3){
                sv[r3][0] = xs[r3*8+ci][t+3];    // xx = t-1+kw -> idx xx+4 = t+3+kw
                sv[r3][1] = xs[r3*8+ci][t+4];
                sv[r3][2] = xs[r3*8+ci][t+5];
            }
            const float* gwp = gw + (cc*8 + ci)*9;     // gw[e][ci][kh][kw], e-stride 288
            #pragma unroll
            for(int e=0;e<8;++e){
                #pragma unroll
                for(int kh=0;kh<3;++kh){
                    #pragma unroll
                    for(int kw=0;kw<3;++kw){
                        g[e] = fmaf(sv[kh][kw], gwp[e*288 + kh*3 + kw], g[e]);
                    }
                }
            }
        }
    }

    {
        float v1b=-1e30f, v2b=-1e30f, v3b=-1e30f, r1=0.f, r2=0.f; int i1=-1, i2=-1;
        #pragma unroll
        for(int e=0;e<8;e++){
            float se = 1.f/(1.f + expf(-g[e]));
            float be = se + gb[e];
            if(be > v1b){ v3b=v2b; v2b=v1b; r2=r1; i2=i1; v1b=be; r1=se; i1=e; }
            else if(be > v2b){ v3b=v2b; v2b=be; r2=se; i2=e; }
            else if(be > v3b){ v3b=be; }
        }
        if(v2b - v3b < 2e-5f){                   // too close to call in fp32 -> fp64 fixup pass
            int slot = atomicAdd(cnt, 1);
            if(slot < MAXFIX) fixlist[slot] = (b << 16) | (y << 8) | t;
        }
        float m  = fmaxf(r1, r2);
        float e1 = expf(r1-m), e2 = expf(r2-m);
        float inv = 1.f/(e1+e2);
        float w1 = e1*inv, w2 = e2*inv;          // ROUTE_SCALE = 1
        bf16x8 ov;
        #pragma unroll
        for(int e=0;e<8;e++){
            float dv = (e==i1) ? w1 : ((e==i2) ? w2 : 0.f);
            ov[e] = f2bf(dv);
        }
        *(bf16x8*)(route + ((size_t)(b*256 + y)*256 + t)*8) = ov;
    }
}

// ---- fixup: fp64 re-selection for flagged pixels (rare) ----
__global__ __launch_bounds__(256) void fixup_kernel(const float* __restrict__ x,
                                                    const float* __restrict__ gw,
                                                    const float* __restrict__ gb,
                                                    const int* __restrict__ cnt,
                                                    const int* __restrict__ fixlist,
                                                    short* __restrict__ route){
    int n = *cnt; if(n > MAXFIX) n = MAXFIX;
    for(int idx = blockIdx.x*256 + threadIdx.x; idx < n; idx += 16*256){
        int pix = fixlist[idx];
        int b  = pix >> 16, y = (pix >> 8) & 255, xx = pix & 255;
        const float* xim = x + (size_t)b*XIM;
        double gd[8];
        #pragma unroll
        for(int e=0;e<8;e++) gd[e] = 0.0;
        for(int ci=0; ci<32; ++ci){
            for(int kh=0; kh<3; ++kh){
                int yy = y + kh - 1;
                if(yy < 0 || yy >= 256) continue;
                const float* xr = xim + ((size_t)ci*256 + yy)*256;
                for(int kw=0; kw<3; ++kw){
                    int xc = xx + kw - 1;
                    if(xc < 0 || xc >= 256) continue;
                    double xv = (double)xr[xc];
                    #pragma unroll
                    for(int e=0;e<8;e++) gd[e] += xv * (double)gw[e*288 + ci*9 + kh*3 + kw];
                }
            }
        }
        double b1=-1e30, b2=-1e30; double rr1=0.0, rr2=0.0; int j1=-1, j2=-1;
        #pragma unroll
        for(int e=0;e<8;e++){
            double sd = 1.0/(1.0 + exp(-gd[e]));
            double bd = sd + (double)gb[e];
            if(bd > b1){ b2=b1; rr2=rr1; j2=j1; b1=bd; rr1=sd; j1=e; }
            else if(bd > b2){ b2=bd; rr2=sd; j2=e; }
        }
        float r1 = (float)rr1, r2 = (float)rr2;
        float m  = fmaxf(r1, r2);
        float e1 = expf(r1-m), e2 = expf(r2-m);
        float inv = 1.f/(e1+e2);
        float w1 = e1*inv, w2 = e2*inv;
        bf16x8 ov;
        #pragma unroll
        for(int e=0;e<8;e++){
            float dv = (e==j1) ? w1 : ((e==j2) ? w2 : 0.f);
            ov[e] = f2bf(dv);
        }
        *(bf16x8*)(route + (size_t)pix*8) = ov;
    }
}

// ---- main: r6 structure, no NT stores, no reg cap (allocator sizes for demand ~190 regs) ----
// WG tile: 8 rows x 32 cols, 4 waves (2 rows each). MFMA 32x32x16: A=weights(M=cout), B=x(N=px).
__global__ __launch_bounds__(256) void moe_main(const float* __restrict__ x,
                                                const short* __restrict__ wt2,
                                                const short* __restrict__ route,
                                                float* __restrict__ out){
    __shared__ __align__(16) short xt[10*4*34*8];    // [row10][cio4][px34][8ci] bf16, 21.76 KB
    __shared__ __align__(16) short wlds[2*9216];     // dbuf: [tap9][cio4][cout32][8ci], 2x18 KB
    int raw = blockIdx.x;                            // 2048; XCD chunk swizzle
    int wg  = (raw & 7)*256 + (raw >> 3);
    int b   = wg >> 8;
    int y0  = ((wg >> 3) & 31) * 8;
    int x0  = (wg & 7) * 32;
    int t   = threadIdx.x;
    int wv  = t >> 6, l = t & 63, col = l & 31, hi = l >> 5;

    // issue async stage of expert 0 -> buf0 (overlaps x staging)
    #pragma unroll
    for(int j=0;j<5;++j){
        int chunk = wv + 4*j;                        // wave-uniform predicate
        if(chunk < 18) glds16(wt2 + chunk*512 + l*8, wlds + chunk*512);
    }

    const float* xim = x + (size_t)b*XIM;
    {   // stage x tile (with halo) -> bf16 LDS
        int px = t & 31;
        #pragma unroll 4
        for(int i=0;i<40;i++){
            int pair = i*8 + (t>>5);                 // row*32+ci
            int row = pair >> 5, ci = pair & 31;
            int yy = y0 - 1 + row, xx = x0 - 1 + px;
            float v = (yy>=0 && yy<256 && xx>=0 && xx<256) ? xim[((size_t)ci*256+yy)*256+xx] : 0.f;
            xt[((row*4 + (ci>>3))*34 + px)*8 + (ci&7)] = f2bf(v);
        }
    }
    #pragma unroll
    for(int k=0;k<3;k++){                            // halo cols px=32,33
        int p = t + k*256;
        if(p < 640){
            int pair = p >> 1, px = 32 + (p & 1);
            int row = pair >> 5, ci = pair & 31;
            int yy = y0 - 1 + row, xx = x0 - 1 + px;
            float v = (yy>=0 && yy<256 && xx>=0 && xx<256) ? xim[((size_t)ci*256+yy)*256+xx] : 0.f;
            xt[((row*4 + (ci>>3))*34 + px)*8 + (ci&7)] = f2bf(v);
        }
    }
    bf16x8 biasA = *(const bf16x8*)(wt2 + 92160 + col*16 + hi*8);   // biasmat[c][k] frag

    __syncthreads();                                 // xt + expert0 staged (drains vmcnt+lgkmcnt)

    // B fragments -> registers, read ONCE (shared by all 9 experts): 24 ds_read_b128
    bf16x8 Bf[4][2][3];                              // [row-off][ci-half][kw]
    #pragma unroll
    for(int r=0;r<4;++r)
        #pragma unroll
        for(int hf=0;hf<2;++hf)
            #pragma unroll
            for(int kw=0;kw<3;++kw){
                int rowi = 2*wv + r;
                int cio  = hf*2 + hi;
                Bf[r][hf][kw] = *(const bf16x8*)(&xt[((rowi*4 + cio)*34 + col + kw)*8]);
            }

    bf16x8 rfrag[2];
    bf16x8 ones = {};
    ones[0] = (short)0x3F80;                         // bf16 1.0 (k=8 row selects sb)
    f32x16 oa[2];
    #pragma unroll
    for(int ct=0; ct<2; ++ct){
        int yy = y0 + 2*wv + ct;
        rfrag[ct] = *(const bf16x8*)(route + ((size_t)(b*256 + yy)*256 + x0 + col)*8);
        bf16x8 bb = hi ? ones : rfrag[ct];
        f32x16 z = {};
        oa[ct] = __builtin_amdgcn_mfma_f32_32x32x16_bf16(biasA, bb, z, 0,0,0);
    }

    #pragma unroll
    for(int e=0; e<9; ++e){                          // experts 0..7, then shared (8)
        const int cur = e & 1;
        if(e < 8){                                   // prefetch next expert -> other buffer
            const short* src = wt2 + (e+1)*9216;
            short* dst = wlds + (cur^1)*9216;
            #pragma unroll
            for(int j=0;j<5;++j){
                int chunk = wv + 4*j;
                if(chunk < 18) glds16(src + chunk*512 + l*8, dst + chunk*512);
            }
        }
        const short* wb = wlds + cur*9216;
        f32x16 acc[2] = {};
        #pragma unroll
        for(int s=0; s<18; ++s){                     // K=288: tap=s>>1, ci-half=s&1
            const int tap = s >> 1;
            const int kh = tap/3, kw = tap - kh*3, hf = s & 1;
            bf16x8 a = *(const bf16x8*)(&wb[((tap*4 + hf*2 + hi)*32 + col)*8]);
            acc[0] = __builtin_amdgcn_mfma_f32_32x32x16_bf16(a, Bf[kh  ][hf][kw], acc[0], 0,0,0);
            acc[1] = __builtin_amdgcn_mfma_f32_32x32x16_bf16(a, Bf[kh+1][hf][kw], acc[1], 0,0,0);
        }
        #pragma unroll
        for(int ct=0; ct<2; ++ct){
            float d = (e < 8) ? bf2f(rfrag[ct][e]) : 1.0f;
            #pragma unroll
            for(int r=0;r<16;r++) oa[ct][r] += d*acc[ct][r];
        }
        if(e < 8) __syncthreads();                   // next buf staged; cur reads done before overwrite
    }

    float* ob = out + (size_t)b*XIM;
    #pragma unroll
    for(int ct=0; ct<2; ++ct){
        int yy = y0 + 2*wv + ct;
        #pragma unroll
        for(int r=0;r<16;r++){
            int c = hi*4 + (r&3) + 8*(r>>2);         // C/D: col=lane&31, row=(r&3)+8*(r>>2)+4*hi
            ob[((size_t)c*256 + yy)*256 + x0 + col] = oa[ct][r];
        }
    }
}

extern "C" void kernel_launch(void* const* d_in, const int* in_sizes, int n_in,
                              void* d_out, int out_size, void* d_ws, size_t ws_size,
                              hipStream_t stream){
    (void)in_sizes; (void)n_in; (void)out_size; (void)ws_size;
    const float* x   = (const float*)d_in[0];
    const float* gw  = (const float*)d_in[1];
    const float* gb  = (const float*)d_in[2];
    const float* ew  = (const float*)d_in[3];
    const float* ebv = (const float*)d_in[4];
    const float* sw  = (const float*)d_in[5];
    const float* sbv = (const float*)d_in[6];
    float* out = (float*)d_out;

    short* route = (short*)d_ws;                          // 524288 px * 8 bf16 = 8.39 MB
    short* wt2   = route + (size_t)8*256*256*8;           // 92160 + 512 bf16
    int*   cnt   = (int*)(wt2 + 92672);
    int*   fixlist = cnt + 1;                             // MAXFIX ints

    zero_cnt    <<<dim3(1),    dim3(64),  0, stream>>>(cnt);
    prep_weights<<<dim3(362),  dim3(256), 0, stream>>>(ew, sw, ebv, sbv, wt2);
    gate_kernel <<<dim3(2048), dim3(256), 0, stream>>>(x, gw, gb, route, cnt, fixlist);
    fixup_kernel<<<dim3(16),   dim3(256), 0, stream>>>(x, gw, gb, cnt, fixlist, route);
    moe_main    <<<dim3(2048), dim3(256), 0, stream>>>(x, wt2, route, out);
}

// Round 9
// 371.757 us; speedup vs baseline: 2.6282x; 1.1120x over previous
//
#include <hip/hip_runtime.h>

typedef __attribute__((ext_vector_type(8)))  short bf16x8;   // 8 bf16 = 4 VGPR MFMA operand
typedef __attribute__((ext_vector_type(16))) float f32x16;   // 32x32 MFMA accumulator

#define XIM (32*256*256)
#define MAXFIX 16384

__device__ __forceinline__ short f2bf(float f){
    unsigned int u = __builtin_bit_cast(unsigned int, f);
    u += 0x7fffu + ((u >> 16) & 1u);           // RNE, no NaN inputs here
    return (short)(u >> 16);
}
__device__ __forceinline__ float bf2f(short s){
    unsigned int u = ((unsigned int)(unsigned short)s) << 16;
    return __builtin_bit_cast(float, u);
}
__device__ __forceinline__ void glds16(const short* g, short* l){
    __builtin_amdgcn_global_load_lds(
        (const __attribute__((address_space(1))) unsigned int*)g,
        (__attribute__((address_space(3))) unsigned int*)l,
        16, 0, 0);
}

__global__ void zero_cnt(int* cnt){ if(threadIdx.x == 0) *cnt = 0; }

// ---- prep: weights -> bf16 wt2[es(10)][tap(9)][cio(4)][cout(32)][8ci]; + biasmat[c(32)][k(16)] ----
__global__ __launch_bounds__(256) void prep_weights(const float* __restrict__ ew,
                                                    const float* __restrict__ sw,
                                                    const float* __restrict__ ebv,
                                                    const float* __restrict__ sbv,
                                                    short* __restrict__ wt2){
    int i = blockIdx.x * 256 + threadIdx.x;      // 362 blocks
    if(i < 92160){
        int c7  = i & 7;
        int col = (i >> 3) & 31;                 // cout
        int cio = (i >> 8) & 3;                  // ci octet
        int rest = i >> 10;                      // 0..89
        int tap = rest % 9;
        int es  = rest / 9;                      // 0..9
        int ci  = cio*8 + c7;
        float v;
        if(es < 8)       v = ew[((es*32 + col)*32 + ci)*9 + tap];
        else if(es == 8) v = sw[(col*32 + ci)*9 + tap];
        else             v = 0.f;
        wt2[i] = f2bf(v);
    } else if(i < 92160 + 512){                  // biasmat: k<8 -> eb[k][c], k==8 -> sb[c], else 0
        int j = i - 92160, c = j >> 4, k = j & 15;
        float v = (k < 8) ? ebv[k*32 + c] : ((k == 8) ? sbv[c] : 0.f);
        wt2[i] = f2bf(v);
    }
}

// ---- gate: 512 blocks, 4 rows/thread; LDS-tiled fp32 conv -> top2 -> softmax -> route ----
__global__ __launch_bounds__(256) void gate_kernel(const float* __restrict__ x,
                                                   const float* __restrict__ gw,
                                                   const float* __restrict__ gb,
                                                   short* __restrict__ route,
                                                   int* __restrict__ cnt,
                                                   int* __restrict__ fixlist){
    __shared__ float xs[24][264];                // [r6*4+cid][4+xx] fp32, 25.3 KB
    int raw = blockIdx.x;                        // 512; XCD chunk swizzle (512%8==0)
    int wg  = (raw & 7)*64 + (raw >> 3);
    int b   = wg >> 6;
    int y0  = (wg & 63) * 4;                     // 4 output rows per block
    int t   = threadIdx.x;                       // column
    int wv  = t >> 6, lane = t & 63;
    const float* xim = x + (size_t)b * XIM;

    if(t < 48){                                  // edge zeros (xx=-1 -> [3], xx=256 -> [260]); persist
        int s2 = t >> 1;
        if(t & 1) xs[s2][260] = 0.f; else xs[s2][3] = 0.f;
    }

    float g[4][8];
    #pragma unroll
    for(int pr=0;pr<4;++pr)
        #pragma unroll
        for(int e=0;e<8;++e) g[pr][e] = 0.f;

    for(int cc=0; cc<8; ++cc){                   // ci chunks of 4
        __syncthreads();                         // prev reads done (also publishes edge zeros)
        #pragma unroll
        for(int sg=0; sg<6; ++sg){               // wave stages 6 of 24 segments via float4
            int seg = wv*6 + sg;
            int r6  = seg >> 2;                  // staged rows y0-1 .. y0+4
            int cid = seg & 3;
            int ci  = cc*4 + cid;
            int yy  = y0 - 1 + r6;
            const float* xr = xim + ((size_t)ci*256 + yy)*256;
            float4 v = make_float4(0.f,0.f,0.f,0.f);
            if(yy >= 0 && yy < 256) v = *(const float4*)(xr + lane*4);
            *(float4*)(&xs[seg][4 + lane*4]) = v;
        }
        __syncthreads();
        #pragma unroll
        for(int cid=0; cid<4; ++cid){
            int ci = cc*4 + cid;
            float sv[6][3];
            #pragma unroll
            for(int r=0;r<6;++r){
                sv[r][0] = xs[r*4+cid][t+3];     // xx = t-1+kw -> idx xx+4 = t+3+kw
                sv[r][1] = xs[r*4+cid][t+4];
                sv[r][2] = xs[r*4+cid][t+5];
            }
            const float* gwp = gw + ci*9;        // gw[e][ci][kh][kw], e-stride 288
            #pragma unroll
            for(int e=0;e<8;++e){
                #pragma unroll
                for(int kh=0;kh<3;++kh){
                    #pragma unroll
                    for(int kw=0;kw<3;++kw){
                        float w = gwp[e*288 + kh*3 + kw];
                        #pragma unroll
                        for(int pr=0;pr<4;++pr)
                            g[pr][e] = fmaf(sv[pr+kh][kw], w, g[pr][e]);
                    }
                }
            }
        }
    }

    #pragma unroll
    for(int pr=0; pr<4; ++pr){
        int y = y0 + pr;
        float v1b=-1e30f, v2b=-1e30f, v3b=-1e30f, r1=0.f, r2=0.f; int i1=-1, i2=-1;
        #pragma unroll
        for(int e=0;e<8;e++){
            float se = 1.f/(1.f + expf(-g[pr][e]));
            float be = se + gb[e];
            if(be > v1b){ v3b=v2b; v2b=v1b; r2=r1; i2=i1; v1b=be; r1=se; i1=e; }
            else if(be > v2b){ v3b=v2b; v2b=be; r2=se; i2=e; }
            else if(be > v3b){ v3b=be; }
        }
        if(v2b - v3b < 2e-5f){                   // too close to call in fp32 -> fp64 fixup pass
            int slot = atomicAdd(cnt, 1);
            if(slot < MAXFIX) fixlist[slot] = (b << 16) | (y << 8) | t;
        }
        float m  = fmaxf(r1, r2);
        float e1 = expf(r1-m), e2 = expf(r2-m);
        float inv = 1.f/(e1+e2);
        float w1 = e1*inv, w2 = e2*inv;          // ROUTE_SCALE = 1
        bf16x8 ov;
        #pragma unroll
        for(int e=0;e<8;e++){
            float dv = (e==i1) ? w1 : ((e==i2) ? w2 : 0.f);
            ov[e] = f2bf(dv);
        }
        *(bf16x8*)(route + ((size_t)(b*256 + y)*256 + t)*8) = ov;
    }
}

// ---- fixup: fp64 re-selection for flagged pixels (rare) ----
__global__ __launch_bounds__(256) void fixup_kernel(const float* __restrict__ x,
                                                    const float* __restrict__ gw,
                                                    const float* __restrict__ gb,
                                                    const int* __restrict__ cnt,
                                                    const int* __restrict__ fixlist,
                                                    short* __restrict__ route){
    int n = *cnt; if(n > MAXFIX) n = MAXFIX;
    for(int idx = blockIdx.x*256 + threadIdx.x; idx < n; idx += 16*256){
        int pix = fixlist[idx];
        int b  = pix >> 16, y = (pix >> 8) & 255, xx = pix & 255;
        const float* xim = x + (size_t)b*XIM;
        double gd[8];
        #pragma unroll
        for(int e=0;e<8;e++) gd[e] = 0.0;
        for(int ci=0; ci<32; ++ci){
            for(int kh=0; kh<3; ++kh){
                int yy = y + kh - 1;
                if(yy < 0 || yy >= 256) continue;
                const float* xr = xim + ((size_t)ci*256 + yy)*256;
                for(int kw=0; kw<3; ++kw){
                    int xc = xx + kw - 1;
                    if(xc < 0 || xc >= 256) continue;
                    double xv = (double)xr[xc];
                    #pragma unroll
                    for(int e=0;e<8;e++) gd[e] += xv * (double)gw[e*288 + ci*9 + kh*3 + kw];
                }
            }
        }
        double b1=-1e30, b2=-1e30; double rr1=0.0, rr2=0.0; int j1=-1, j2=-1;
        #pragma unroll
        for(int e=0;e<8;e++){
            double sd = 1.0/(1.0 + exp(-gd[e]));
            double bd = sd + (double)gb[e];
            if(bd > b1){ b2=b1; rr2=rr1; j2=j1; b1=bd; rr1=sd; j1=e; }
            else if(bd > b2){ b2=bd; rr2=sd; j2=e; }
        }
        float r1 = (float)rr1, r2 = (float)rr2;
        float m  = fmaxf(r1, r2);
        float e1 = expf(r1-m), e2 = expf(r2-m);
        float inv = 1.f/(e1+e2);
        float w1 = e1*inv, w2 = e2*inv;
        bf16x8 ov;
        #pragma unroll
        for(int e=0;e<8;e++){
            float dv = (e==j1) ? w1 : ((e==j2) ? w2 : 0.f);
            ov[e] = f2bf(dv);
        }
        *(bf16x8*)(route + (size_t)pix*8) = ov;
    }
}

// ---- main: 1 row/wave for low VGPR + 3 waves/SIMD; block tile 4 rows x 32 cols ----
// MFMA 32x32x16: A=weights(M=cout), B=x(N=px). Weights glds-double-buffered per expert.
__global__ __launch_bounds__(256) void moe_main(const float* __restrict__ x,
                                                const short* __restrict__ wt2,
                                                const short* __restrict__ route,
                                                float* __restrict__ out){
    __shared__ __align__(16) short xt[6*4*34*8];     // [row6][cio4][px34][8ci] bf16, 13.06 KB
    __shared__ __align__(16) short wlds[2*9216];     // dbuf: [tap9][cio4][cout32][8ci], 2x18 KB
    int raw = blockIdx.x;                            // 4096; XCD chunk swizzle (4096%8==0)
    int wg  = (raw & 7)*512 + (raw >> 3);
    int b   = wg >> 9;
    int rem = wg & 511;
    int y0  = (rem >> 3) * 4;
    int x0  = (rem & 7) * 32;
    int t   = threadIdx.x;
    int wv  = t >> 6, l = t & 63, col = l & 31, hi = l >> 5;

    // issue async stage of expert 0 -> buf0 (overlaps x staging)
    #pragma unroll
    for(int j=0;j<5;++j){
        int chunk = wv + 4*j;                        // wave-uniform predicate
        if(chunk < 18) glds16(wt2 + chunk*512 + l*8, wlds + chunk*512);
    }

    const float* xim = x + (size_t)b*XIM;
    {   // stage x tile rows y0-1..y0+4 (with halo) -> bf16 LDS
        int px = t & 31;
        #pragma unroll 4
        for(int i=0;i<24;i++){
            int pair = i*8 + (t>>5);                 // row*32+ci, 192 pairs
            int row = pair >> 5, ci = pair & 31;
            int yy = y0 - 1 + row, xx = x0 - 1 + px;
            float v = (yy>=0 && yy<256 && xx>=0 && xx<256) ? xim[((size_t)ci*256+yy)*256+xx] : 0.f;
            xt[((row*4 + (ci>>3))*34 + px)*8 + (ci&7)] = f2bf(v);
        }
    }
    #pragma unroll
    for(int k=0;k<2;k++){                            // halo cols px=32,33 (384 entries)
        int p = t + k*256;
        if(p < 384){
            int pair = p >> 1, px = 32 + (p & 1);
            int row = pair >> 5, ci = pair & 31;
            int yy = y0 - 1 + row, xx = x0 - 1 + px;
            float v = (yy>=0 && yy<256 && xx>=0 && xx<256) ? xim[((size_t)ci*256+yy)*256+xx] : 0.f;
            xt[((row*4 + (ci>>3))*34 + px)*8 + (ci&7)] = f2bf(v);
        }
    }
    bf16x8 biasA = *(const bf16x8*)(wt2 + 92160 + col*16 + hi*8);   // biasmat[c][k] frag

    asm volatile("s_waitcnt vmcnt(0)" ::: "memory");
    __syncthreads();                                 // xt + expert0 staged

    // B fragments -> registers, read ONCE (shared by all 9 experts): 18 ds_read_b128
    // wave wv -> output row y0+wv, needs xt rows wv..wv+2
    bf16x8 Bf[3][2][3];                              // [kh][ci-half][kw]
    #pragma unroll
    for(int kh=0;kh<3;++kh)
        #pragma unroll
        for(int hf=0;hf<2;++hf)
            #pragma unroll
            for(int kw=0;kw<3;++kw)
                Bf[kh][hf][kw] = *(const bf16x8*)(&xt[(((wv+kh)*4 + hf*2 + hi)*34 + col + kw)*8]);

    int yy = y0 + wv;
    bf16x8 rfrag = *(const bf16x8*)(route + ((size_t)(b*256 + yy)*256 + x0 + col)*8);
    bf16x8 ones = {};
    ones[0] = (short)0x3F80;                         // bf16 1.0 (k=8 row selects sb)
    f32x16 z = {};
    f32x16 oa = __builtin_amdgcn_mfma_f32_32x32x16_bf16(biasA, hi ? ones : rfrag, z, 0,0,0);

    #pragma unroll
    for(int e=0; e<9; ++e){                          // experts 0..7, then shared (8)
        const int cur = e & 1;
        if(e < 8){                                   // prefetch next expert -> other buffer
            const short* src = wt2 + (e+1)*9216;
            short* dst = wlds + (cur^1)*9216;
            #pragma unroll
            for(int j=0;j<5;++j){
                int chunk = wv + 4*j;
                if(chunk < 18) glds16(src + chunk*512 + l*8, dst + chunk*512);
            }
        }
        const short* wb = wlds + cur*9216;
        f32x16 acc = {};
        #pragma unroll
        for(int s=0; s<18; ++s){                     // K=288: tap=s>>1, ci-half=s&1
            const int tap = s >> 1;
            const int kh = tap/3, kw = tap - kh*3, hf = s & 1;
            bf16x8 a = *(const bf16x8*)(&wb[((tap*4 + hf*2 + hi)*32 + col)*8]);
            acc = __builtin_amdgcn_mfma_f32_32x32x16_bf16(a, Bf[kh][hf][kw], acc, 0,0,0);
        }
        float d = (e < 8) ? bf2f(rfrag[e]) : 1.0f;
        #pragma unroll
        for(int r=0;r<16;r++) oa[r] += d*acc[r];
        if(e < 8) __syncthreads();                   // next buf staged; cur reads done before overwrite
    }

    float* ob = out + (size_t)b*XIM;
    #pragma unroll
    for(int r=0;r<16;r++){
        int c = hi*4 + (r&3) + 8*(r>>2);             // C/D: col=lane&31, row=(r&3)+8*(r>>2)+4*hi
        ob[((size_t)c*256 + yy)*256 + x0 + col] = oa[r];
    }
}

extern "C" void kernel_launch(void* const* d_in, const int* in_sizes, int n_in,
                              void* d_out, int out_size, void* d_ws, size_t ws_size,
                              hipStream_t stream){
    (void)in_sizes; (void)n_in; (void)out_size; (void)ws_size;
    const float* x   = (const float*)d_in[0];
    const float* gw  = (const float*)d_in[1];
    const float* gb  = (const float*)d_in[2];
    const float* ew  = (const float*)d_in[3];
    const float* ebv = (const float*)d_in[4];
    const float* sw  = (const float*)d_in[5];
    const float* sbv = (const float*)d_in[6];
    float* out = (float*)d_out;

    short* route = (short*)d_ws;                          // 524288 px * 8 bf16 = 8.39 MB
    short* wt2   = route + (size_t)8*256*256*8;           // 92160 + 512 bf16
    int*   cnt   = (int*)(wt2 + 92672);
    int*   fixlist = cnt + 1;                             // MAXFIX ints

    zero_cnt    <<<dim3(1),    dim3(64),  0, stream>>>(cnt);
    prep_weights<<<dim3(362),  dim3(256), 0, stream>>>(ew, sw, ebv, sbv, wt2);
    gate_kernel <<<dim3(512),  dim3(256), 0, stream>>>(x, gw, gb, route, cnt, fixlist);
    fixup_kernel<<<dim3(16),   dim3(256), 0, stream>>>(x, gw, gb, cnt, fixlist, route);
    moe_main    <<<dim3(4096), dim3(256), 0, stream>>>(x, wt2, route, out);
}